// Round 1
// baseline (263.503 us; speedup 1.0000x reference)
//
#include <hip/hip_runtime.h>

// Multibin binary conv:  y = conv2d(sign(x), sum_m sign(W_m), SAME) + sum_m b_m
// x: [16,256,256,32] f32   W: [4,3,3,32,32] f32   b: [4,32] f32
// out: [16,256,256,32] f32
//
// Strategy: implicit GEMM with mfma_f32_32x32x16_bf16.
//   A = im2col(sign(x)) as +-1 bf16 (0 for SAME-padding halo)
//   B = wsumT[co][k], k=(dh*3+dw)*32+ci, values in {-4,-2,0,2,4} (exact bf16)
// Per workgroup: strip of RH=16 rows x 128 cols, rolling 4-slot LDS row buffer.
// 4 waves, each owns one 32-pixel x 32-cout tile per output row (18 MFMAs, K=288).
// All 18 B fragments held in VGPRs (72 regs), loaded once per wave.

#define RH     16
#define NSTAGE 130          // staged pixels per row (128 + 2 halo)
#define PITCH  40           // u16 per pixel (32 cin + 8 pad; 80B keeps 16B align, bank stride 20)
#define SLOT   (NSTAGE * PITCH)   // 5200 u16 per row slot; 4 slots = 41600 B

typedef __attribute__((ext_vector_type(8)))  short  short8;
typedef __attribute__((ext_vector_type(8)))  __bf16 bf16x8;
typedef __attribute__((ext_vector_type(16))) float  f32x16;

__device__ __forceinline__ unsigned int pack2(float a, float b, bool ok) {
    // sign(x) in bf16: +1.0 = 0x3F80, -1.0 = 0xBF80; padding -> 0
    unsigned int lo = ok ? ((a >= 0.0f) ? 0x3F80u : 0xBF80u) : 0u;
    unsigned int hi = ok ? ((b >= 0.0f) ? 0x3F80u : 0xBF80u) : 0u;
    return lo | (hi << 16);
}

// ---------------- prep: wsumT[co][288] bf16 + bsum[32] f32 into d_ws ----------------
__global__ void prep_kernel(const float* __restrict__ W, const float* __restrict__ bias,
                            unsigned short* __restrict__ wsT, float* __restrict__ bsum) {
    int t = blockIdx.x * 256 + threadIdx.x;
    if (t < 9216) {
        int k   = t >> 5;          // 0..287
        int co  = t & 31;
        int tap = k >> 5;          // dh*3+dw
        int ci  = k & 31;
        float s = 0.0f;
        #pragma unroll
        for (int m = 0; m < 4; ++m) {
            float w = W[(m * 9 + tap) * 1024 + ci * 32 + co];
            s += (w >= 0.0f) ? 1.0f : -1.0f;
        }
        unsigned int u = __builtin_bit_cast(unsigned int, s);  // exact bf16 (low mantissa = 0)
        wsT[co * 288 + k] = (unsigned short)(u >> 16);
    }
    if (t < 32) {
        float s = 0.0f;
        #pragma unroll
        for (int m = 0; m < 4; ++m) s += bias[m * 32 + t];
        bsum[t] = s;
    }
}

// stage one image row (absrow) of the strip into an LDS slot (load+convert+write)
__device__ __forceinline__ void stage_row(const float* __restrict__ x,
                                          unsigned short* __restrict__ dst,
                                          int bimg, int c0, int absrow, int tid) {
    bool rowok = (absrow >= 0) && (absrow < 256);
    const float* rowp = x + (long)((bimg * 256 + absrow) * 256) * 32;
    #pragma unroll
    for (int p = 0; p < 5; ++p) {
        int f = tid + p * 256;            // 1040 float4s: 130 pixels x 8 chunks
        int pix = f >> 3, ch = f & 7;
        if (pix < NSTAGE) {
            int col = c0 - 1 + pix;
            bool ok = rowok && (col >= 0) && (col < 256);
            float4 v = ok ? *(const float4*)(rowp + col * 32 + ch * 4)
                          : make_float4(0.f, 0.f, 0.f, 0.f);
            *(uint2*)(dst + pix * PITCH + ch * 4) =
                make_uint2(pack2(v.x, v.y, ok), pack2(v.z, v.w, ok));
        }
    }
}

__global__ __launch_bounds__(256) void conv_kernel(const float* __restrict__ x,
                                                   const unsigned short* __restrict__ wsT,
                                                   const float* __restrict__ bsum,
                                                   float* __restrict__ out) {
    __shared__ unsigned short lds[4 * SLOT];

    const int tid  = threadIdx.x;
    const int lane = tid & 63;
    const int wv   = tid >> 6;        // wave 0..3 -> 32-col tile within strip
    const int lrow = lane & 31;       // A: pixel row / B,D: cout column
    const int lk   = lane >> 5;       // k-half selector

    const int bs   = blockIdx.x;      // 512 = 16 bimg x 16 rowstrips x 2 colstrips
    const int c0   = (bs & 1) * 128;
    const int r0   = ((bs >> 1) & 15) * RH;
    const int bimg = bs >> 5;

    // B fragments: lane holds B[k = t*16 + lk*8 + j][n = lrow] = wsT[lrow][k]
    bf16x8 bfrag[18];
    #pragma unroll
    for (int t = 0; t < 18; ++t)
        bfrag[t] = *(const bf16x8*)(wsT + lrow * 288 + t * 16 + lk * 8);
    const float bsv = bsum[lrow];

    // pre-stage rows r0-1, r0, r0+1 -> slots 0,1,2
    #pragma unroll
    for (int pre = 0; pre < 3; ++pre)
        stage_row(x, lds + pre * SLOT, bimg, c0, r0 - 1 + pre, tid);
    __syncthreads();

    const int a_base = (wv * 32 + lrow) * PITCH + lk * 8;

    for (int i = 0; i < RH; ++i) {
        const int r = r0 + i;
        const bool do_pf = (i < RH - 1);
        const int absrow = r + 2;                 // next-next row
        const bool rowok = do_pf && (absrow < 256);
        const float* rowp = x + (long)((bimg * 256 + absrow) * 256) * 32;

        // ---- issue prefetch loads (latency hides behind MFMA block) ----
        float4 buf[5];
        #pragma unroll
        for (int p = 0; p < 5; ++p) {
            int f = tid + p * 256;
            int pix = f >> 3, ch = f & 7;
            int col = c0 - 1 + pix;
            bool ok = rowok && (pix < NSTAGE) && (col >= 0) && (col < 256);
            buf[p] = ok ? *(const float4*)(rowp + col * 32 + ch * 4)
                        : make_float4(0.f, 0.f, 0.f, 0.f);
        }

        // ---- compute output row r from slots (i, i+1, i+2) & 3 ----
        f32x16 acc = {};
        #pragma unroll
        for (int dh = 0; dh < 3; ++dh) {
            const unsigned short* sb = lds + ((i + dh) & 3) * SLOT + a_base;
            #pragma unroll
            for (int dw = 0; dw < 3; ++dw) {
                #pragma unroll
                for (int hf = 0; hf < 2; ++hf) {
                    bf16x8 a = *(const bf16x8*)(sb + dw * PITCH + hf * 16);
                    acc = __builtin_amdgcn_mfma_f32_32x32x16_bf16(
                              a, bfrag[(dh * 3 + dw) * 2 + hf], acc, 0, 0, 0);
                }
            }
        }

        // ---- store: D col = lrow (cout), row = (reg&3)+8*(reg>>2)+4*lk (pixel) ----
        float* op = out + ((long)((bimg * 256 + r) * 256 + c0 + wv * 32)) * 32 + lrow;
        #pragma unroll
        for (int reg = 0; reg < 16; ++reg) {
            int pr = (reg & 3) + 8 * (reg >> 2) + 4 * lk;
            op[pr * 32] = acc[reg] + bsv;
        }

        // ---- convert + LDS write of prefetched row into slot (i+3)&3 ----
        if (do_pf) {
            unsigned short* dst = lds + ((i + 3) & 3) * SLOT;
            #pragma unroll
            for (int p = 0; p < 5; ++p) {
                int f = tid + p * 256;
                int pix = f >> 3, ch = f & 7;
                if (pix < NSTAGE) {
                    int col = c0 - 1 + pix;
                    bool ok = (absrow < 256) && (col >= 0) && (col < 256);
                    *(uint2*)(dst + pix * PITCH + ch * 4) =
                        make_uint2(pack2(buf[p].x, buf[p].y, ok),
                                   pack2(buf[p].z, buf[p].w, ok));
                }
            }
        }
        __syncthreads();
    }
}

extern "C" void kernel_launch(void* const* d_in, const int* in_sizes, int n_in,
                              void* d_out, int out_size, void* d_ws, size_t ws_size,
                              hipStream_t stream) {
    const float* x    = (const float*)d_in[0];   // [16,256,256,32]
    const float* W    = (const float*)d_in[1];   // [4,3,3,32,32]
    const float* bias = (const float*)d_in[2];   // [4,32]
    float* out = (float*)d_out;

    unsigned short* wsT = (unsigned short*)d_ws;            // 9216 bf16 = 18432 B
    float* bsum = (float*)((char*)d_ws + 18432);            // 32 f32

    prep_kernel<<<36, 256, 0, stream>>>(W, bias, wsT, bsum);
    conv_kernel<<<512, 256, 0, stream>>>(x, wsT, bsum, out);
}